// Round 2
// baseline (829.619 us; speedup 1.0000x reference)
//
#include <hip/hip_runtime.h>

#define NB    512
#define CIN   12
#define TIN   5000
#define C1    32
#define T1    496
#define T2    95
#define LATD  32
#define HIDD  64

// workspace layout (float offsets)
#define OFS_STATS 0        // 256 floats: [bn1_sum 32][bn1_sq 32][bn2_sum 32][bn2_sq 32][s1 32][sh1 32][s2 32][sh2 32]
#define OFS_W1P   256      // 12*32*54 = 20736
#define OFS_W2P   20992    // 32*32*26 = 26624
#define OFS_Y1    47616    // 512*32*496 = 8126464
#define OFS_Y2    8174080  // 512*32*95  = 1556480
#define OFS_XS    OFS_Y1   // xs[95][512][32] aliases y1 (y1 dead after conv2)

// ---------------- prep: zero stats + repack weights ----------------
__global__ void prep_kernel(const float* __restrict__ w1, const float* __restrict__ w2,
                            float* __restrict__ ws) {
    int idx = blockIdx.x * 256 + threadIdx.x;
    if (idx < 256) ws[idx] = 0.f;
    int j = idx - 256;
    if (j >= 0 && j < 20736) {            // w1p[ic][oc][54]
        int ic = j / 1728, r = j % 1728, oc = r / 54, k = r % 54;
        ws[OFS_W1P + j] = (k < 50) ? w1[oc * 600 + ic * 50 + k] : 0.f;
    }
    int j2 = idx - 20992;
    if (j2 >= 0 && j2 < 26624) {          // w2p[ic][oc][26]
        int ic = j2 / 832, r = j2 % 832, oc = r / 26, k = r % 26;
        ws[OFS_W2P + j2] = (k < 25) ? w2[oc * 800 + ic * 25 + k] : 0.f;
    }
}

// ---------------- conv1 + bias, fused BN1 stats ----------------
// grid 1024: b = bx>>1, t-tile (256) = bx&1. block 128: ocg=tid&3 (8 oc each), tg=tid>>2 (8 t each)
// __launch_bounds__(128, 2): cap VGPR at 256 (kernel needs ~120; heuristic cap at
// lower VGPRs would spill the 64-reg accumulator tile)
__global__ __launch_bounds__(128, 2) void conv1_kernel(const float* __restrict__ x,
                                                       const float* __restrict__ b1,
                                                       float* __restrict__ ws) {
    const float* w1p = ws + OFS_W1P;
    float* y1 = ws + OFS_Y1;
    float* stats = ws + OFS_STATS;
    int b  = blockIdx.x >> 1;
    int t0 = (blockIdx.x & 1) * 256;
    int tid = threadIdx.x;
    int ocg = tid & 3, tg = tid >> 2;
    int oc0 = ocg * 8, lt0 = tg * 8;
    int xbase = 82 * tg;                      // skewed LDS base

    __shared__ __align__(16) float xs_s[2664];    // 2600 + skew
    __shared__ __align__(16) float ws_s[1728];    // 32*54
    __shared__ float sred[128];

    float acc[8][8];
#pragma unroll
    for (int a = 0; a < 8; ++a)
#pragma unroll
        for (int c = 0; c < 8; ++c) acc[a][c] = 0.f;

    const float* xb = x + (size_t)b * (CIN * TIN) + t0 * 10;
    int nvalid = TIN - t0 * 10;               // 5000 or 2440

    for (int ic = 0; ic < CIN; ++ic) {
        __syncthreads();
        // stage x row (2600 floats, skew +2 per 80)
        for (int i = tid; i < 650; i += 128) {
            int src = 4 * i;
            const float* gp = xb + ic * TIN + src;
            float4 v;
            if (src + 4 <= nvalid) {
                v = *(const float4*)gp;
            } else {
                v.x = (src + 0 < nvalid) ? gp[0] : 0.f;
                v.y = (src + 1 < nvalid) ? gp[1] : 0.f;
                v.z = (src + 2 < nvalid) ? gp[2] : 0.f;
                v.w = (src + 3 < nvalid) ? gp[3] : 0.f;
            }
            int dst = src + (i / 20) * 2;
            float2 lo; lo.x = v.x; lo.y = v.y;
            float2 hi; hi.x = v.z; hi.y = v.w;
            *(float2*)&xs_s[dst]     = lo;
            *(float2*)&xs_s[dst + 2] = hi;
        }
        // stage weights for this ic: 1728 floats
        for (int i = tid; i < 432; i += 128)
            *(float4*)&ws_s[4 * i] = *(const float4*)(w1p + ic * 1728 + 4 * i);
        __syncthreads();

#pragma unroll 1
        for (int kp = 0; kp < 25; ++kp) {
            const int k = kp * 2;
            float2 wv[8], xv[8];
#pragma unroll
            for (int jo = 0; jo < 8; ++jo)
                wv[jo] = *(const float2*)&ws_s[(oc0 + jo) * 54 + k];
#pragma unroll
            for (int jt = 0; jt < 8; ++jt) {
                int r = jt * 10 + k;
                int ad = xbase + r + ((r >= 80) ? 2 : 0);
                xv[jt] = *(const float2*)&xs_s[ad];
            }
#pragma unroll
            for (int jo = 0; jo < 8; ++jo)
#pragma unroll
                for (int jt = 0; jt < 8; ++jt)
                    acc[jo][jt] = fmaf(wv[jo].y, xv[jt].y, fmaf(wv[jo].x, xv[jt].x, acc[jo][jt]));
        }
    }

    float bias[8];
#pragma unroll
    for (int jo = 0; jo < 8; ++jo) bias[jo] = b1[oc0 + jo];

    bool tvalid = (t0 + lt0) <= (T1 - 8);     // whole 8-t group valid or not
    float psum[8], psq[8];
#pragma unroll
    for (int jo = 0; jo < 8; ++jo) {
        float s = 0.f, q = 0.f;
        if (tvalid) {
            float tmp[8];
#pragma unroll
            for (int jt = 0; jt < 8; ++jt) {
                float v = acc[jo][jt] + bias[jo];
                tmp[jt] = v; s += v; q = fmaf(v, v, q);
            }
            float* yrow = y1 + (size_t)(b * 32 + oc0 + jo) * T1 + t0 + lt0;
            float4 o0; o0.x = tmp[0]; o0.y = tmp[1]; o0.z = tmp[2]; o0.w = tmp[3];
            float4 o1; o1.x = tmp[4]; o1.y = tmp[5]; o1.z = tmp[6]; o1.w = tmp[7];
            *(float4*)yrow       = o0;
            *(float4*)(yrow + 4) = o1;
        }
        psum[jo] = s; psq[jo] = q;
    }
    // reduce over tg (lane stride 4) within each wave
#pragma unroll
    for (int off = 32; off >= 4; off >>= 1) {
#pragma unroll
        for (int jo = 0; jo < 8; ++jo) {
            psum[jo] += __shfl_down(psum[jo], off, 64);
            psq[jo]  += __shfl_down(psq[jo],  off, 64);
        }
    }
    int lane = tid & 63, wvi = tid >> 6;
    if (lane < 4) {
#pragma unroll
        for (int jo = 0; jo < 8; ++jo) {
            sred[((wvi * 4 + lane) * 8 + jo) * 2 + 0] = psum[jo];
            sred[((wvi * 4 + lane) * 8 + jo) * 2 + 1] = psq[jo];
        }
    }
    __syncthreads();
    if (tid < 64) {
        int oc = tid >> 1, which = tid & 1;
        int og = oc >> 3, jo = oc & 7;
        float v = sred[((0 * 4 + og) * 8 + jo) * 2 + which] +
                  sred[((1 * 4 + og) * 8 + jo) * 2 + which];
        atomicAdd(&stats[which * 32 + oc], v);
    }
}

// ---------------- BN stats -> scale/shift ----------------
__global__ void bnstats_kernel(const float* __restrict__ g, const float* __restrict__ bparm,
                               float* __restrict__ ws, int base_in, int base_out, float invN) {
    int oc = threadIdx.x;
    if (oc < 32) {
        float* stats = ws + OFS_STATS;
        float mean = stats[base_in + oc] * invN;
        float var  = stats[base_in + 32 + oc] * invN - mean * mean;
        float s = g[oc] * rsqrtf(var + 1e-5f);
        stats[base_out + oc]      = s;
        stats[base_out + 32 + oc] = bparm[oc] - mean * s;
    }
}

// ---------------- conv2 (BN1+ReLU folded at stage time) + BN2 stats ----------------
// grid 512 (b). block 192: ocg=tid&7 (4 oc each), tg=tid>>3 (0..23, 4 t each)
__global__ __launch_bounds__(192, 2) void conv2_kernel(const float* __restrict__ b2,
                                                       float* __restrict__ ws) {
    const float* w2p = ws + OFS_W2P;
    const float* y1 = ws + OFS_Y1;
    float* y2 = ws + OFS_Y2;
    float* stats = ws + OFS_STATS;
    int b = blockIdx.x;
    int tid = threadIdx.x;
    int ocg = tid & 7, tg = tid >> 3;
    int oc0 = ocg * 4, lt0 = tg * 4;

    __shared__ __align__(16) float a1s[500];
    __shared__ __align__(16) float w2s[832];
    __shared__ float sred[192];

    float acc[4][4];
#pragma unroll
    for (int a = 0; a < 4; ++a)
#pragma unroll
        for (int c = 0; c < 4; ++c) acc[a][c] = 0.f;

    for (int ic = 0; ic < 32; ++ic) {
        __syncthreads();
        float s1  = stats[128 + ic];
        float sh1 = stats[160 + ic];
        const float* yrow = y1 + (size_t)(b * 32 + ic) * T1;
        for (int i = tid; i < 124; i += 192) {
            float4 v = *(const float4*)(yrow + 4 * i);
            v.x = fmaxf(fmaf(v.x, s1, sh1), 0.f);
            v.y = fmaxf(fmaf(v.y, s1, sh1), 0.f);
            v.z = fmaxf(fmaf(v.z, s1, sh1), 0.f);
            v.w = fmaxf(fmaf(v.w, s1, sh1), 0.f);
            *(float4*)&a1s[4 * i] = v;
        }
        for (int i = tid; i < 208; i += 192)
            *(float4*)&w2s[4 * i] = *(const float4*)(w2p + ic * 832 + 4 * i);
        __syncthreads();

#pragma unroll 1
        for (int kp = 0; kp < 12; ++kp) {
            const int k = kp * 2;
            float2 wv[4];
#pragma unroll
            for (int jo = 0; jo < 4; ++jo)
                wv[jo] = *(const float2*)&w2s[(oc0 + jo) * 26 + k];
            float x0[4], x1[4];
#pragma unroll
            for (int jt = 0; jt < 4; ++jt) {
                int a = 20 * tg + 5 * jt + k;
                x0[jt] = a1s[a]; x1[jt] = a1s[a + 1];
            }
#pragma unroll
            for (int jo = 0; jo < 4; ++jo)
#pragma unroll
                for (int jt = 0; jt < 4; ++jt)
                    acc[jo][jt] = fmaf(wv[jo].y, x1[jt], fmaf(wv[jo].x, x0[jt], acc[jo][jt]));
        }
        // k = 24 tail
        float wt[4];
#pragma unroll
        for (int jo = 0; jo < 4; ++jo) wt[jo] = w2s[(oc0 + jo) * 26 + 24];
#pragma unroll
        for (int jt = 0; jt < 4; ++jt) {
            float xt_ = a1s[20 * tg + 5 * jt + 24];
#pragma unroll
            for (int jo = 0; jo < 4; ++jo) acc[jo][jt] = fmaf(wt[jo], xt_, acc[jo][jt]);
        }
    }

    float bias[4];
#pragma unroll
    for (int jo = 0; jo < 4; ++jo) bias[jo] = b2[oc0 + jo];

    float psum[4], psq[4];
#pragma unroll
    for (int jo = 0; jo < 4; ++jo) {
        float s = 0.f, q = 0.f;
#pragma unroll
        for (int jt = 0; jt < 4; ++jt) {
            int t2 = lt0 + jt;
            if (t2 < T2) {
                float v = acc[jo][jt] + bias[jo];
                y2[(size_t)(b * 32 + oc0 + jo) * T2 + t2] = v;
                s += v; q = fmaf(v, v, q);
            }
        }
        psum[jo] = s; psq[jo] = q;
    }
#pragma unroll
    for (int off = 32; off >= 8; off >>= 1) {
#pragma unroll
        for (int jo = 0; jo < 4; ++jo) {
            psum[jo] += __shfl_down(psum[jo], off, 64);
            psq[jo]  += __shfl_down(psq[jo],  off, 64);
        }
    }
    int lane = tid & 63, wvi = tid >> 6;   // 3 waves
    if (lane < 8) {
#pragma unroll
        for (int jo = 0; jo < 4; ++jo) {
            sred[((wvi * 8 + lane) * 4 + jo) * 2 + 0] = psum[jo];
            sred[((wvi * 8 + lane) * 4 + jo) * 2 + 1] = psq[jo];
        }
    }
    __syncthreads();
    if (tid < 64) {
        int oc = tid >> 1, which = tid & 1;
        int og = oc >> 2, jo = oc & 3;
        float v = 0.f;
#pragma unroll
        for (int w = 0; w < 3; ++w)
            v += sred[((w * 8 + og) * 4 + jo) * 2 + which];
        atomicAdd(&stats[64 + which * 32 + oc], v);
    }
}

// ---------------- projection + LayerNorm, writes xs[t][b][l] ----------------
__global__ __launch_bounds__(256, 2) void proj_kernel(const float* __restrict__ pw,
                                                      const float* __restrict__ pb,
                                                      const float* __restrict__ lng,
                                                      const float* __restrict__ lnb,
                                                      float* __restrict__ ws) {
    int b = blockIdx.x;
    int tid = threadIdx.x;
    __shared__ float a2s[3040];       // [f][t]
    __shared__ float pws[1056];       // [l][33]
    const float* stats = ws + OFS_STATS;
    const float* y2 = ws + OFS_Y2 + (size_t)b * (32 * T2);
    float* xsg = ws + OFS_XS;

    for (int f = 0; f < 32; ++f) {
        float s2  = stats[192 + f];
        float sh2 = stats[224 + f];
        if (tid < T2)
            a2s[f * T2 + tid] = fmaxf(fmaf(y2[f * T2 + tid], s2, sh2), 0.f);
    }
    for (int i = tid; i < 1024; i += 256)
        pws[(i >> 5) * 33 + (i & 31)] = pw[i];

    int l = tid & 31, ts = tid >> 5;
    float pbv = pb[l], lg = lng[l], lb = lnb[l];
    __syncthreads();

    for (int it = 0; it < 12; ++it) {
        int t = ts + 8 * it;
        if (t < T2) {
            float v = pbv;
#pragma unroll
            for (int f = 0; f < 32; ++f)
                v = fmaf(a2s[f * T2 + t], pws[l * 33 + f], v);
            // LN over the 32-lane group
            float sum = v;
#pragma unroll
            for (int off = 16; off >= 1; off >>= 1) sum += __shfl_xor(sum, off, 64);
            float mean = sum * (1.f / 32.f);
            float d = v - mean;
            float q = d * d;
#pragma unroll
            for (int off = 16; off >= 1; off >>= 1) q += __shfl_xor(q, off, 64);
            float o = d * rsqrtf(q * (1.f / 32.f) + 1e-5f) * lg + lb;
            xsg[(size_t)t * (NB * 32) + b * 32 + l] = o;
        }
    }
}

// ---------------- PLRNN scan + pooled mean + output projection ----------------
// grid 512 (b), block 64 (one wave). lane l = lane&31, half = lane>>5.
// __launch_bounds__(64, 1): allow up to 512 VGPRs — the hot loop keeps ~130 live
// floats (Wc32+WT32+Ah16+h32+work); a 96-VGPR heuristic cap spills in the
// 95-step dependent chain (R1: 362us -> spill-bound).
__global__ __launch_bounds__(64, 1) void scan_kernel(const float* __restrict__ Am,
                                                     const float* __restrict__ Wm,
                                                     const float* __restrict__ hbp,
                                                     const float* __restrict__ ow,
                                                     const float* __restrict__ ob,
                                                     const float* __restrict__ ws,
                                                     float* __restrict__ out) {
    int b = blockIdx.x;
    int lane = threadIdx.x;
    int l = lane & 31, half = lane >> 5;
    __shared__ __align__(16) float hs[32];
    __shared__ __align__(16) float hds[64];
    __shared__ float ows[1056];

    float Wc[32], WT[32], Ah[16];
#pragma unroll
    for (int j = 0; j < 32; ++j) Wc[j] = Wm[j * HIDD + lane];          // W[j][lane]
#pragma unroll
    for (int m = 0; m < 32; ++m) WT[m] = Wm[l * HIDD + half * 32 + m]; // W[l][m-half]
#pragma unroll
    for (int j = 0; j < 16; ++j) Ah[j] = Am[l * 32 + half * 16 + j];   // A[l][j-half]
    float hbv = hbp[lane];
    for (int i = lane; i < 1024; i += 64)
        ows[(i >> 5) * 33 + (i & 31)] = ow[i];

    const float* xsg = ws + OFS_XS + b * 32;
    if (lane < 32) hs[l] = 0.f;
    float xv = xsg[l];
    float pool = 0.f;
    __syncthreads();

    for (int t = 0; t < T2; ++t) {
        __syncthreads();
        float hreg[32];
#pragma unroll
        for (int q = 0; q < 8; ++q) {
            float4 h4 = *(const float4*)&hs[4 * q];
            hreg[4 * q + 0] = h4.x; hreg[4 * q + 1] = h4.y;
            hreg[4 * q + 2] = h4.z; hreg[4 * q + 3] = h4.w;
        }
        // hid matvec: 4 partial accumulators (dep chain 8 deep, not 32)
        float a0 = hbv, a1 = 0.f, a2 = 0.f, a3 = 0.f;
#pragma unroll
        for (int q = 0; q < 8; ++q) {
            a0 = fmaf(Wc[4 * q + 0], hreg[4 * q + 0], a0);
            a1 = fmaf(Wc[4 * q + 1], hreg[4 * q + 1], a1);
            a2 = fmaf(Wc[4 * q + 2], hreg[4 * q + 2], a2);
            a3 = fmaf(Wc[4 * q + 3], hreg[4 * q + 3], a3);
        }
        float hid = fmaxf((a0 + a1) + (a2 + a3), 0.f);
        // lin (A*h) is independent of hid: compute in phase 1, 2 partials
        float l0 = 0.f, l1 = 0.f;
#pragma unroll
        for (int j = 0; j < 8; ++j) {
            l0 = fmaf(Ah[2 * j + 0], hreg[half * 16 + 2 * j + 0], l0);
            l1 = fmaf(Ah[2 * j + 1], hreg[half * 16 + 2 * j + 1], l1);
        }
        float lin = l0 + l1;
        hds[lane] = hid;
        __syncthreads();
        float n0 = 0.f, n1 = 0.f, n2 = 0.f, n3 = 0.f;
        const float4* hp = (const float4*)&hds[half * 32];
#pragma unroll
        for (int q = 0; q < 8; ++q) {
            float4 d4 = hp[q];
            n0 = fmaf(WT[4 * q + 0], d4.x, n0);
            n1 = fmaf(WT[4 * q + 1], d4.y, n1);
            n2 = fmaf(WT[4 * q + 2], d4.z, n2);
            n3 = fmaf(WT[4 * q + 3], d4.w, n3);
        }
        float part = (n0 + n1) + (n2 + n3) + lin;
        part += __shfl_xor(part, 32, 64);
        float hnew = part + xv;
        pool += hnew;
        if (t + 1 < T2) xv = xsg[(size_t)(t + 1) * (NB * 32) + l];
        if (lane < 32) hs[l] = hnew;   // all hs reads happened before the mid barrier
    }

    __syncthreads();
    if (lane < 32) hs[l] = pool * (1.f / 95.f);
    __syncthreads();
    if (lane < 32) {
        float pm[32];
#pragma unroll
        for (int q = 0; q < 8; ++q) {
            float4 h4 = *(const float4*)&hs[4 * q];
            pm[4 * q + 0] = h4.x; pm[4 * q + 1] = h4.y;
            pm[4 * q + 2] = h4.z; pm[4 * q + 3] = h4.w;
        }
        float o = ob[l];
#pragma unroll
        for (int j = 0; j < 32; ++j) o = fmaf(ows[l * 33 + j], pm[j], o);
        out[b * 32 + l] = o;
    }
}

extern "C" void kernel_launch(void* const* d_in, const int* in_sizes, int n_in,
                              void* d_out, int out_size, void* d_ws, size_t ws_size,
                              hipStream_t stream) {
    (void)in_sizes; (void)n_in; (void)out_size; (void)ws_size;
    const float* x   = (const float*)d_in[0];
    const float* w1  = (const float*)d_in[1];
    const float* b1  = (const float*)d_in[2];
    const float* g1  = (const float*)d_in[3];
    const float* be1 = (const float*)d_in[4];
    const float* w2  = (const float*)d_in[5];
    const float* b2  = (const float*)d_in[6];
    const float* g2  = (const float*)d_in[7];
    const float* be2 = (const float*)d_in[8];
    const float* pw  = (const float*)d_in[9];
    const float* pb  = (const float*)d_in[10];
    const float* lng = (const float*)d_in[11];
    const float* lnb = (const float*)d_in[12];
    const float* Am  = (const float*)d_in[13];
    const float* Wm  = (const float*)d_in[14];
    const float* hb  = (const float*)d_in[15];
    const float* ow  = (const float*)d_in[16];
    const float* ob  = (const float*)d_in[17];
    float* ws  = (float*)d_ws;
    float* out = (float*)d_out;

    prep_kernel<<<186, 256, 0, stream>>>(w1, w2, ws);
    conv1_kernel<<<1024, 128, 0, stream>>>(x, b1, ws);
    bnstats_kernel<<<1, 64, 0, stream>>>(g1, be1, ws, 0, 128, 1.f / 253952.f);
    conv2_kernel<<<512, 192, 0, stream>>>(b2, ws);
    bnstats_kernel<<<1, 64, 0, stream>>>(g2, be2, ws, 64, 192, 1.f / 48640.f);
    proj_kernel<<<512, 256, 0, stream>>>(pw, pb, lng, lnb, ws);
    scan_kernel<<<512, 64, 0, stream>>>(Am, Wm, hb, ow, ob, ws, out);
}

// Round 3
// 513.599 us; speedup vs baseline: 1.6153x; 1.6153x over previous
//
#include <hip/hip_runtime.h>

#define NB    512
#define CIN   12
#define TIN   5000
#define C1    32
#define T1    496
#define T2    95
#define LATD  32
#define HIDD  64

// workspace layout (float offsets)
#define OFS_STATS 0        // 256 floats: [bn1_sum 32][bn1_sq 32][bn2_sum 32][bn2_sq 32][s1 32][sh1 32][s2 32][sh2 32]
#define OFS_W1P   256      // 12*32*54 = 20736
#define OFS_W2P   20992    // 32*32*26 = 26624
#define OFS_Y1    47616    // 512*32*496 = 8126464
#define OFS_Y2    8174080  // 512*32*95  = 1556480
#define OFS_XS    OFS_Y1   // xs[95][512][32] aliases y1 (y1 dead after conv2)

// ---------------- prep: zero stats + repack weights ----------------
__global__ void prep_kernel(const float* __restrict__ w1, const float* __restrict__ w2,
                            float* __restrict__ ws) {
    int idx = blockIdx.x * 256 + threadIdx.x;
    if (idx < 256) ws[idx] = 0.f;
    int j = idx - 256;
    if (j >= 0 && j < 20736) {            // w1p[ic][oc][54]
        int ic = j / 1728, r = j % 1728, oc = r / 54, k = r % 54;
        ws[OFS_W1P + j] = (k < 50) ? w1[oc * 600 + ic * 50 + k] : 0.f;
    }
    int j2 = idx - 20992;
    if (j2 >= 0 && j2 < 26624) {          // w2p[ic][oc][26]
        int ic = j2 / 832, r = j2 % 832, oc = r / 26, k = r % 26;
        ws[OFS_W2P + j2] = (k < 25) ? w2[oc * 800 + ic * 25 + k] : 0.f;
    }
}

// ---------------- conv1 + bias, fused BN1 stats ----------------
// grid 1024: b = bx>>1, t-tile (256) = bx&1. block 128: ocg=tid&3 (8 oc each), tg=tid>>2 (8 t each)
__global__ __launch_bounds__(128, 2) void conv1_kernel(const float* __restrict__ x,
                                                       const float* __restrict__ b1,
                                                       float* __restrict__ ws) {
    const float* w1p = ws + OFS_W1P;
    float* y1 = ws + OFS_Y1;
    float* stats = ws + OFS_STATS;
    int b  = blockIdx.x >> 1;
    int t0 = (blockIdx.x & 1) * 256;
    int tid = threadIdx.x;
    int ocg = tid & 3, tg = tid >> 2;
    int oc0 = ocg * 8, lt0 = tg * 8;
    int xbase = 82 * tg;                      // skewed LDS base

    __shared__ __align__(16) float xs_s[2664];    // 2600 + skew
    __shared__ __align__(16) float ws_s[1728];    // 32*54
    __shared__ float sred[128];

    float acc[8][8];
#pragma unroll
    for (int a = 0; a < 8; ++a)
#pragma unroll
        for (int c = 0; c < 8; ++c) acc[a][c] = 0.f;

    const float* xb = x + (size_t)b * (CIN * TIN) + t0 * 10;
    int nvalid = TIN - t0 * 10;               // 5000 or 2440

    for (int ic = 0; ic < CIN; ++ic) {
        __syncthreads();
        // stage x row (2600 floats, skew +2 per 80)
        for (int i = tid; i < 650; i += 128) {
            int src = 4 * i;
            const float* gp = xb + ic * TIN + src;
            float4 v;
            if (src + 4 <= nvalid) {
                v = *(const float4*)gp;
            } else {
                v.x = (src + 0 < nvalid) ? gp[0] : 0.f;
                v.y = (src + 1 < nvalid) ? gp[1] : 0.f;
                v.z = (src + 2 < nvalid) ? gp[2] : 0.f;
                v.w = (src + 3 < nvalid) ? gp[3] : 0.f;
            }
            int dst = src + (i / 20) * 2;
            float2 lo; lo.x = v.x; lo.y = v.y;
            float2 hi; hi.x = v.z; hi.y = v.w;
            *(float2*)&xs_s[dst]     = lo;
            *(float2*)&xs_s[dst + 2] = hi;
        }
        // stage weights for this ic: 1728 floats
        for (int i = tid; i < 432; i += 128)
            *(float4*)&ws_s[4 * i] = *(const float4*)(w1p + ic * 1728 + 4 * i);
        __syncthreads();

#pragma unroll 1
        for (int kp = 0; kp < 25; ++kp) {
            const int k = kp * 2;
            float2 wv[8], xv[8];
#pragma unroll
            for (int jo = 0; jo < 8; ++jo)
                wv[jo] = *(const float2*)&ws_s[(oc0 + jo) * 54 + k];
#pragma unroll
            for (int jt = 0; jt < 8; ++jt) {
                int r = jt * 10 + k;
                int ad = xbase + r + ((r >= 80) ? 2 : 0);
                xv[jt] = *(const float2*)&xs_s[ad];
            }
#pragma unroll
            for (int jo = 0; jo < 8; ++jo)
#pragma unroll
                for (int jt = 0; jt < 8; ++jt)
                    acc[jo][jt] = fmaf(wv[jo].y, xv[jt].y, fmaf(wv[jo].x, xv[jt].x, acc[jo][jt]));
        }
    }

    float bias[8];
#pragma unroll
    for (int jo = 0; jo < 8; ++jo) bias[jo] = b1[oc0 + jo];

    bool tvalid = (t0 + lt0) <= (T1 - 8);
    float psum[8], psq[8];
#pragma unroll
    for (int jo = 0; jo < 8; ++jo) {
        float s = 0.f, q = 0.f;
        if (tvalid) {
            float tmp[8];
#pragma unroll
            for (int jt = 0; jt < 8; ++jt) {
                float v = acc[jo][jt] + bias[jo];
                tmp[jt] = v; s += v; q = fmaf(v, v, q);
            }
            float* yrow = y1 + (size_t)(b * 32 + oc0 + jo) * T1 + t0 + lt0;
            float4 o0; o0.x = tmp[0]; o0.y = tmp[1]; o0.z = tmp[2]; o0.w = tmp[3];
            float4 o1; o1.x = tmp[4]; o1.y = tmp[5]; o1.z = tmp[6]; o1.w = tmp[7];
            *(float4*)yrow       = o0;
            *(float4*)(yrow + 4) = o1;
        }
        psum[jo] = s; psq[jo] = q;
    }
#pragma unroll
    for (int off = 32; off >= 4; off >>= 1) {
#pragma unroll
        for (int jo = 0; jo < 8; ++jo) {
            psum[jo] += __shfl_down(psum[jo], off, 64);
            psq[jo]  += __shfl_down(psq[jo],  off, 64);
        }
    }
    int lane = tid & 63, wvi = tid >> 6;
    if (lane < 4) {
#pragma unroll
        for (int jo = 0; jo < 8; ++jo) {
            sred[((wvi * 4 + lane) * 8 + jo) * 2 + 0] = psum[jo];
            sred[((wvi * 4 + lane) * 8 + jo) * 2 + 1] = psq[jo];
        }
    }
    __syncthreads();
    if (tid < 64) {
        int oc = tid >> 1, which = tid & 1;
        int og = oc >> 3, jo = oc & 7;
        float v = sred[((0 * 4 + og) * 8 + jo) * 2 + which] +
                  sred[((1 * 4 + og) * 8 + jo) * 2 + which];
        atomicAdd(&stats[which * 32 + oc], v);
    }
}

// ---------------- BN stats -> scale/shift ----------------
__global__ void bnstats_kernel(const float* __restrict__ g, const float* __restrict__ bparm,
                               float* __restrict__ ws, int base_in, int base_out, float invN) {
    int oc = threadIdx.x;
    if (oc < 32) {
        float* stats = ws + OFS_STATS;
        float mean = stats[base_in + oc] * invN;
        float var  = stats[base_in + 32 + oc] * invN - mean * mean;
        float s = g[oc] * rsqrtf(var + 1e-5f);
        stats[base_out + oc]      = s;
        stats[base_out + 32 + oc] = bparm[oc] - mean * s;
    }
}

// ---------------- conv2 (BN1+ReLU folded at stage time) + BN2 stats ----------------
__global__ __launch_bounds__(192, 2) void conv2_kernel(const float* __restrict__ b2,
                                                       float* __restrict__ ws) {
    const float* w2p = ws + OFS_W2P;
    const float* y1 = ws + OFS_Y1;
    float* y2 = ws + OFS_Y2;
    float* stats = ws + OFS_STATS;
    int b = blockIdx.x;
    int tid = threadIdx.x;
    int ocg = tid & 7, tg = tid >> 3;
    int oc0 = ocg * 4, lt0 = tg * 4;

    __shared__ __align__(16) float a1s[500];
    __shared__ __align__(16) float w2s[832];
    __shared__ float sred[192];

    float acc[4][4];
#pragma unroll
    for (int a = 0; a < 4; ++a)
#pragma unroll
        for (int c = 0; c < 4; ++c) acc[a][c] = 0.f;

    for (int ic = 0; ic < 32; ++ic) {
        __syncthreads();
        float s1  = stats[128 + ic];
        float sh1 = stats[160 + ic];
        const float* yrow = y1 + (size_t)(b * 32 + ic) * T1;
        for (int i = tid; i < 124; i += 192) {
            float4 v = *(const float4*)(yrow + 4 * i);
            v.x = fmaxf(fmaf(v.x, s1, sh1), 0.f);
            v.y = fmaxf(fmaf(v.y, s1, sh1), 0.f);
            v.z = fmaxf(fmaf(v.z, s1, sh1), 0.f);
            v.w = fmaxf(fmaf(v.w, s1, sh1), 0.f);
            *(float4*)&a1s[4 * i] = v;
        }
        for (int i = tid; i < 208; i += 192)
            *(float4*)&w2s[4 * i] = *(const float4*)(w2p + ic * 832 + 4 * i);
        __syncthreads();

#pragma unroll 1
        for (int kp = 0; kp < 12; ++kp) {
            const int k = kp * 2;
            float2 wv[4];
#pragma unroll
            for (int jo = 0; jo < 4; ++jo)
                wv[jo] = *(const float2*)&w2s[(oc0 + jo) * 26 + k];
            float x0[4], x1[4];
#pragma unroll
            for (int jt = 0; jt < 4; ++jt) {
                int a = 20 * tg + 5 * jt + k;
                x0[jt] = a1s[a]; x1[jt] = a1s[a + 1];
            }
#pragma unroll
            for (int jo = 0; jo < 4; ++jo)
#pragma unroll
                for (int jt = 0; jt < 4; ++jt)
                    acc[jo][jt] = fmaf(wv[jo].y, x1[jt], fmaf(wv[jo].x, x0[jt], acc[jo][jt]));
        }
        // k = 24 tail
        float wt[4];
#pragma unroll
        for (int jo = 0; jo < 4; ++jo) wt[jo] = w2s[(oc0 + jo) * 26 + 24];
#pragma unroll
        for (int jt = 0; jt < 4; ++jt) {
            float xt_ = a1s[20 * tg + 5 * jt + 24];
#pragma unroll
            for (int jo = 0; jo < 4; ++jo) acc[jo][jt] = fmaf(wt[jo], xt_, acc[jo][jt]);
        }
    }

    float bias[4];
#pragma unroll
    for (int jo = 0; jo < 4; ++jo) bias[jo] = b2[oc0 + jo];

    float psum[4], psq[4];
#pragma unroll
    for (int jo = 0; jo < 4; ++jo) {
        float s = 0.f, q = 0.f;
#pragma unroll
        for (int jt = 0; jt < 4; ++jt) {
            int t2 = lt0 + jt;
            if (t2 < T2) {
                float v = acc[jo][jt] + bias[jo];
                y2[(size_t)(b * 32 + oc0 + jo) * T2 + t2] = v;
                s += v; q = fmaf(v, v, q);
            }
        }
        psum[jo] = s; psq[jo] = q;
    }
#pragma unroll
    for (int off = 32; off >= 8; off >>= 1) {
#pragma unroll
        for (int jo = 0; jo < 4; ++jo) {
            psum[jo] += __shfl_down(psum[jo], off, 64);
            psq[jo]  += __shfl_down(psq[jo],  off, 64);
        }
    }
    int lane = tid & 63, wvi = tid >> 6;   // 3 waves
    if (lane < 8) {
#pragma unroll
        for (int jo = 0; jo < 4; ++jo) {
            sred[((wvi * 8 + lane) * 4 + jo) * 2 + 0] = psum[jo];
            sred[((wvi * 8 + lane) * 4 + jo) * 2 + 1] = psq[jo];
        }
    }
    __syncthreads();
    if (tid < 64) {
        int oc = tid >> 1, which = tid & 1;
        int og = oc >> 2, jo = oc & 3;
        float v = 0.f;
#pragma unroll
        for (int w = 0; w < 3; ++w)
            v += sred[((w * 8 + og) * 4 + jo) * 2 + which];
        atomicAdd(&stats[64 + which * 32 + oc], v);
    }
}

// ---------------- projection + LayerNorm, writes xs[t][b][l] ----------------
__global__ __launch_bounds__(256, 2) void proj_kernel(const float* __restrict__ pw,
                                                      const float* __restrict__ pb,
                                                      const float* __restrict__ lng,
                                                      const float* __restrict__ lnb,
                                                      float* __restrict__ ws) {
    int b = blockIdx.x;
    int tid = threadIdx.x;
    __shared__ float a2s[3040];       // [f][t]
    __shared__ float pws[1056];       // [l][33]
    const float* stats = ws + OFS_STATS;
    const float* y2 = ws + OFS_Y2 + (size_t)b * (32 * T2);
    float* xsg = ws + OFS_XS;

    for (int f = 0; f < 32; ++f) {
        float s2  = stats[192 + f];
        float sh2 = stats[224 + f];
        if (tid < T2)
            a2s[f * T2 + tid] = fmaxf(fmaf(y2[f * T2 + tid], s2, sh2), 0.f);
    }
    for (int i = tid; i < 1024; i += 256)
        pws[(i >> 5) * 33 + (i & 31)] = pw[i];

    int l = tid & 31, ts = tid >> 5;
    float pbv = pb[l], lg = lng[l], lb = lnb[l];
    __syncthreads();

    for (int it = 0; it < 12; ++it) {
        int t = ts + 8 * it;
        if (t < T2) {
            float v = pbv;
#pragma unroll
            for (int f = 0; f < 32; ++f)
                v = fmaf(a2s[f * T2 + t], pws[l * 33 + f], v);
            float sum = v;
#pragma unroll
            for (int off = 16; off >= 1; off >>= 1) sum += __shfl_xor(sum, off, 64);
            float mean = sum * (1.f / 32.f);
            float d = v - mean;
            float q = d * d;
#pragma unroll
            for (int off = 16; off >= 1; off >>= 1) q += __shfl_xor(q, off, 64);
            float o = d * rsqrtf(q * (1.f / 32.f) + 1e-5f) * lg + lb;
            xsg[(size_t)t * (NB * 32) + b * 32 + l] = o;
        }
    }
}

// ---------------- PLRNN scan + pooled mean + output projection ----------------
// grid 512 (b), block 64 (one wave). lane l = lane&31, half = lane>>5.
// CRITICAL: no register array may be indexed by a runtime value (e.g. `half`) —
// dynamic indexing demotes the array to scratch (private VMEM) and the 95-step
// dependent chain becomes scratch-reload-bound (R1/R2: 360-400us). The
// half-dependent h slice is read straight from LDS (dynamic LDS base is native).
__global__ __launch_bounds__(64)
__attribute__((amdgpu_waves_per_eu(1, 1)))
void scan_kernel(const float* __restrict__ Am,
                 const float* __restrict__ Wm,
                 const float* __restrict__ hbp,
                 const float* __restrict__ ow,
                 const float* __restrict__ ob,
                 const float* __restrict__ ws,
                 float* __restrict__ out) {
    int b = blockIdx.x;
    int lane = threadIdx.x;
    int l = lane & 31, half = lane >> 5;
    __shared__ __align__(16) float hs[32];
    __shared__ __align__(16) float hds[64];
    __shared__ float ows[1056];

    float Wc[32], WT[32], Ah[16];
#pragma unroll
    for (int j = 0; j < 32; ++j) Wc[j] = Wm[j * HIDD + lane];          // W[j][lane]
#pragma unroll
    for (int m = 0; m < 32; ++m) WT[m] = Wm[l * HIDD + half * 32 + m]; // W[l][m-half]
#pragma unroll
    for (int j = 0; j < 16; ++j) Ah[j] = Am[l * 32 + half * 16 + j];   // A[l][j-half]
    float hbv = hbp[lane];
    for (int i = lane; i < 1024; i += 64)
        ows[(i >> 5) * 33 + (i & 31)] = ow[i];

    const float* xsg = ws + OFS_XS + b * 32;
    if (lane < 32) hs[l] = 0.f;
    float xv = xsg[l];
    float pool = 0.f;
    __syncthreads();

    for (int t = 0; t < T2; ++t) {
        __syncthreads();
        // phase 1a: hid matvec, h read with CONSTANT LDS offsets
        float4 hv[8];
#pragma unroll
        for (int q = 0; q < 8; ++q) hv[q] = *(const float4*)&hs[4 * q];
        float a0 = hbv, a1 = 0.f, a2 = 0.f, a3 = 0.f;
#pragma unroll
        for (int q = 0; q < 8; ++q) {
            a0 = fmaf(Wc[4 * q + 0], hv[q].x, a0);
            a1 = fmaf(Wc[4 * q + 1], hv[q].y, a1);
            a2 = fmaf(Wc[4 * q + 2], hv[q].z, a2);
            a3 = fmaf(Wc[4 * q + 3], hv[q].w, a3);
        }
        float hid = fmaxf((a0 + a1) + (a2 + a3), 0.f);
        // phase 1b: lin = A-half . h-half; dynamic BASE into LDS, constant reg idx
        float4 hl[4];
#pragma unroll
        for (int q = 0; q < 4; ++q) hl[q] = *(const float4*)&hs[half * 16 + 4 * q];
        float l0 = 0.f, l1 = 0.f;
#pragma unroll
        for (int q = 0; q < 4; ++q) {
            l0 = fmaf(Ah[4 * q + 0], hl[q].x, l0);
            l1 = fmaf(Ah[4 * q + 1], hl[q].y, l1);
            l0 = fmaf(Ah[4 * q + 2], hl[q].z, l0);
            l1 = fmaf(Ah[4 * q + 3], hl[q].w, l1);
        }
        float lin = l0 + l1;
        hds[lane] = hid;
        __syncthreads();
        float n0 = 0.f, n1 = 0.f, n2 = 0.f, n3 = 0.f;
#pragma unroll
        for (int q = 0; q < 8; ++q) {
            float4 d4 = *(const float4*)&hds[half * 32 + 4 * q];
            n0 = fmaf(WT[4 * q + 0], d4.x, n0);
            n1 = fmaf(WT[4 * q + 1], d4.y, n1);
            n2 = fmaf(WT[4 * q + 2], d4.z, n2);
            n3 = fmaf(WT[4 * q + 3], d4.w, n3);
        }
        float part = (n0 + n1) + (n2 + n3) + lin;
        part += __shfl_xor(part, 32, 64);
        float hnew = part + xv;
        pool += hnew;
        if (t + 1 < T2) xv = xsg[(size_t)(t + 1) * (NB * 32) + l];
        if (lane < 32) hs[l] = hnew;   // hs reads of this iter all precede the mid barrier
    }

    __syncthreads();
    if (lane < 32) hs[l] = pool * (1.f / 95.f);
    __syncthreads();
    if (lane < 32) {
        float4 p0 = *(const float4*)&hs[0];
        float4 p1 = *(const float4*)&hs[4];
        float4 p2 = *(const float4*)&hs[8];
        float4 p3 = *(const float4*)&hs[12];
        float4 p4 = *(const float4*)&hs[16];
        float4 p5 = *(const float4*)&hs[20];
        float4 p6 = *(const float4*)&hs[24];
        float4 p7 = *(const float4*)&hs[28];
        float o = ob[l];
        const float* owr = &ows[l * 33];
        o = fmaf(owr[0],  p0.x, o); o = fmaf(owr[1],  p0.y, o);
        o = fmaf(owr[2],  p0.z, o); o = fmaf(owr[3],  p0.w, o);
        o = fmaf(owr[4],  p1.x, o); o = fmaf(owr[5],  p1.y, o);
        o = fmaf(owr[6],  p1.z, o); o = fmaf(owr[7],  p1.w, o);
        o = fmaf(owr[8],  p2.x, o); o = fmaf(owr[9],  p2.y, o);
        o = fmaf(owr[10], p2.z, o); o = fmaf(owr[11], p2.w, o);
        o = fmaf(owr[12], p3.x, o); o = fmaf(owr[13], p3.y, o);
        o = fmaf(owr[14], p3.z, o); o = fmaf(owr[15], p3.w, o);
        o = fmaf(owr[16], p4.x, o); o = fmaf(owr[17], p4.y, o);
        o = fmaf(owr[18], p4.z, o); o = fmaf(owr[19], p4.w, o);
        o = fmaf(owr[20], p5.x, o); o = fmaf(owr[21], p5.y, o);
        o = fmaf(owr[22], p5.z, o); o = fmaf(owr[23], p5.w, o);
        o = fmaf(owr[24], p6.x, o); o = fmaf(owr[25], p6.y, o);
        o = fmaf(owr[26], p6.z, o); o = fmaf(owr[27], p6.w, o);
        o = fmaf(owr[28], p7.x, o); o = fmaf(owr[29], p7.y, o);
        o = fmaf(owr[30], p7.z, o); o = fmaf(owr[31], p7.w, o);
        out[b * 32 + l] = o;
    }
}

extern "C" void kernel_launch(void* const* d_in, const int* in_sizes, int n_in,
                              void* d_out, int out_size, void* d_ws, size_t ws_size,
                              hipStream_t stream) {
    (void)in_sizes; (void)n_in; (void)out_size; (void)ws_size;
    const float* x   = (const float*)d_in[0];
    const float* w1  = (const float*)d_in[1];
    const float* b1  = (const float*)d_in[2];
    const float* g1  = (const float*)d_in[3];
    const float* be1 = (const float*)d_in[4];
    const float* w2  = (const float*)d_in[5];
    const float* b2  = (const float*)d_in[6];
    const float* g2  = (const float*)d_in[7];
    const float* be2 = (const float*)d_in[8];
    const float* pw  = (const float*)d_in[9];
    const float* pb  = (const float*)d_in[10];
    const float* lng = (const float*)d_in[11];
    const float* lnb = (const float*)d_in[12];
    const float* Am  = (const float*)d_in[13];
    const float* Wm  = (const float*)d_in[14];
    const float* hb  = (const float*)d_in[15];
    const float* ow  = (const float*)d_in[16];
    const float* ob  = (const float*)d_in[17];
    float* ws  = (float*)d_ws;
    float* out = (float*)d_out;

    prep_kernel<<<186, 256, 0, stream>>>(w1, w2, ws);
    conv1_kernel<<<1024, 128, 0, stream>>>(x, b1, ws);
    bnstats_kernel<<<1, 64, 0, stream>>>(g1, be1, ws, 0, 128, 1.f / 253952.f);
    conv2_kernel<<<512, 192, 0, stream>>>(b2, ws);
    bnstats_kernel<<<1, 64, 0, stream>>>(g2, be2, ws, 64, 192, 1.f / 48640.f);
    proj_kernel<<<512, 256, 0, stream>>>(pw, pb, lng, lnb, ws);
    scan_kernel<<<512, 64, 0, stream>>>(Am, Wm, hb, ow, ob, ws, out);
}

// Round 4
// 468.619 us; speedup vs baseline: 1.7703x; 1.0960x over previous
//
#include <hip/hip_runtime.h>

#define NB    512
#define CIN   12
#define TIN   5000
#define C1    32
#define T1    496
#define T2    95
#define LATD  32
#define HIDD  64

// workspace layout (float offsets)
#define OFS_STATS 0        // 256 floats
#define OFS_W1P   256      // 12*50*32 = 19200, layout [ic][k][oc]
#define OFS_W2P   19456    // 32*25*32 = 25600, layout [ic][k][oc]
#define OFS_Y1    45056    // 512*32*496 = 8126464
#define OFS_Y2    8171520  // 512*32*95  = 1556480
#define OFS_XS    OFS_Y1   // xs[95][512][32] aliases y1 (y1 dead after conv2)

// ---------------- prep: zero stats + repack weights ----------------
__global__ void prep_kernel(const float* __restrict__ w1, const float* __restrict__ w2,
                            float* __restrict__ ws) {
    int idx = blockIdx.x * 256 + threadIdx.x;
    if (idx < 256) ws[idx] = 0.f;
    int j = idx - 256;
    if (j >= 0 && j < 19200) {            // w1p[ic][k][oc], oc fastest
        int ic = j / 1600, r = j % 1600, k = r / 32, oc = r % 32;
        ws[OFS_W1P + j] = w1[oc * 600 + ic * 50 + k];
    }
    int j2 = idx - 19456;
    if (j2 >= 0 && j2 < 25600) {          // w2p[ic][k][oc]
        int ic = j2 / 800, r = j2 % 800, k = r / 32, oc = r % 32;
        ws[OFS_W2P + j2] = w2[oc * 800 + ic * 25 + k];
    }
}

// ---------------- conv1 + bias, fused BN1 stats ----------------
// grid 1024: b = bx>>1, t-tile (256) = bx&1. block 128: ocg=tid&3 (8 oc), tg=tid>>2 (8 t)
// Weight LDS layout [k][oc]: wv loads are 4x b128/kp, conflict-free (R3 had 2-way
// conflicts on every wv read = ~10k cyc/wave). Double-buffered staging with
// register prefetch overlaps global latency with compute.
__global__ __launch_bounds__(128, 2) void conv1_kernel(const float* __restrict__ x,
                                                       const float* __restrict__ b1,
                                                       float* __restrict__ ws) {
    const float* w1p = ws + OFS_W1P;
    float* y1 = ws + OFS_Y1;
    float* stats = ws + OFS_STATS;
    int b  = blockIdx.x >> 1;
    int t0 = (blockIdx.x & 1) * 256;
    int tid = threadIdx.x;
    int ocg = tid & 3, tg = tid >> 2;
    int oc0 = ocg * 8, lt0 = tg * 8;
    int xbase = 82 * tg;                      // skewed LDS base (reads conflict-free)

    __shared__ __align__(16) float xs_s[2][2664];   // 2600 + skew, double-buffered
    __shared__ __align__(16) float ws_s[2][1600];   // [k][oc] 50*32
    __shared__ float sred[128];

    float acc[8][8];
#pragma unroll
    for (int a = 0; a < 8; ++a)
#pragma unroll
        for (int c = 0; c < 8; ++c) acc[a][c] = 0.f;

    const float* xb = x + (size_t)b * (CIN * TIN) + t0 * 10;
    int nvalid = TIN - t0 * 10;               // 5000 or 2440

    float4 px[6];
    float4 pw[4];

    auto fetch = [&](int ic) {
#pragma unroll
        for (int j = 0; j < 6; ++j) {
            int i = tid + j * 128;
            if (i < 650) {
                int src = 4 * i;
                const float* gp = xb + ic * TIN + src;
                float4 v;
                if (src + 4 <= nvalid) {
                    v = *(const float4*)gp;
                } else {
                    v.x = (src + 0 < nvalid) ? gp[0] : 0.f;
                    v.y = (src + 1 < nvalid) ? gp[1] : 0.f;
                    v.z = (src + 2 < nvalid) ? gp[2] : 0.f;
                    v.w = (src + 3 < nvalid) ? gp[3] : 0.f;
                }
                px[j] = v;
            }
        }
#pragma unroll
        for (int j = 0; j < 4; ++j) {
            int i = tid + j * 128;
            if (i < 400) pw[j] = *(const float4*)(w1p + ic * 1600 + 4 * i);
        }
    };

    fetch(0);
    for (int ic = 0; ic < CIN; ++ic) {
        int cur = ic & 1;
        __syncthreads();                      // buf[cur] free (read 2 iters ago)
#pragma unroll
        for (int j = 0; j < 6; ++j) {
            int i = tid + j * 128;
            if (i < 650) {
                int src = 4 * i;
                int dst = src + (i / 20) * 2; // skew +2 per 80 words
                float2 lo; lo.x = px[j].x; lo.y = px[j].y;
                float2 hi; hi.x = px[j].z; hi.y = px[j].w;
                *(float2*)&xs_s[cur][dst]     = lo;
                *(float2*)&xs_s[cur][dst + 2] = hi;
            }
        }
#pragma unroll
        for (int j = 0; j < 4; ++j) {
            int i = tid + j * 128;
            if (i < 400) *(float4*)&ws_s[cur][4 * i] = pw[j];
        }
        if (ic + 1 < CIN) fetch(ic + 1);      // global loads fly during compute
        __syncthreads();

#pragma unroll 1
        for (int kp = 0; kp < 25; ++kp) {
            const int k = kp * 2;
            const float* wr = &ws_s[cur][k * 32 + oc0];
            float4 w00 = *(const float4*)wr;         // tap k,   oc0..oc0+3
            float4 w01 = *(const float4*)(wr + 4);   // tap k,   oc0+4..7
            float4 w10 = *(const float4*)(wr + 32);  // tap k+1, oc0..oc0+3
            float4 w11 = *(const float4*)(wr + 36);
            float2 xv[8];
#pragma unroll
            for (int jt = 0; jt < 8; ++jt) {
                int r = jt * 10 + k;
                int ad = xbase + r + ((r >= 80) ? 2 : 0);
                xv[jt] = *(const float2*)&xs_s[cur][ad];
            }
            float wk[8]  = {w00.x, w00.y, w00.z, w00.w, w01.x, w01.y, w01.z, w01.w};
            float wk1[8] = {w10.x, w10.y, w10.z, w10.w, w11.x, w11.y, w11.z, w11.w};
#pragma unroll
            for (int jo = 0; jo < 8; ++jo)
#pragma unroll
                for (int jt = 0; jt < 8; ++jt)
                    acc[jo][jt] = fmaf(wk1[jo], xv[jt].y, fmaf(wk[jo], xv[jt].x, acc[jo][jt]));
        }
    }

    float bias[8];
#pragma unroll
    for (int jo = 0; jo < 8; ++jo) bias[jo] = b1[oc0 + jo];

    bool tvalid = (t0 + lt0) <= (T1 - 8);
    float psum[8], psq[8];
#pragma unroll
    for (int jo = 0; jo < 8; ++jo) {
        float s = 0.f, q = 0.f;
        if (tvalid) {
            float tmp[8];
#pragma unroll
            for (int jt = 0; jt < 8; ++jt) {
                float v = acc[jo][jt] + bias[jo];
                tmp[jt] = v; s += v; q = fmaf(v, v, q);
            }
            float* yrow = y1 + (size_t)(b * 32 + oc0 + jo) * T1 + t0 + lt0;
            float4 o0; o0.x = tmp[0]; o0.y = tmp[1]; o0.z = tmp[2]; o0.w = tmp[3];
            float4 o1; o1.x = tmp[4]; o1.y = tmp[5]; o1.z = tmp[6]; o1.w = tmp[7];
            *(float4*)yrow       = o0;
            *(float4*)(yrow + 4) = o1;
        }
        psum[jo] = s; psq[jo] = q;
    }
#pragma unroll
    for (int off = 32; off >= 4; off >>= 1) {
#pragma unroll
        for (int jo = 0; jo < 8; ++jo) {
            psum[jo] += __shfl_down(psum[jo], off, 64);
            psq[jo]  += __shfl_down(psq[jo],  off, 64);
        }
    }
    int lane = tid & 63, wvi = tid >> 6;
    if (lane < 4) {
#pragma unroll
        for (int jo = 0; jo < 8; ++jo) {
            sred[((wvi * 4 + lane) * 8 + jo) * 2 + 0] = psum[jo];
            sred[((wvi * 4 + lane) * 8 + jo) * 2 + 1] = psq[jo];
        }
    }
    __syncthreads();
    if (tid < 64) {
        int oc = tid >> 1, which = tid & 1;
        int og = oc >> 3, jo = oc & 7;
        float v = sred[((0 * 4 + og) * 8 + jo) * 2 + which] +
                  sred[((1 * 4 + og) * 8 + jo) * 2 + which];
        atomicAdd(&stats[which * 32 + oc], v);
    }
}

// ---------------- BN stats -> scale/shift ----------------
__global__ void bnstats_kernel(const float* __restrict__ g, const float* __restrict__ bparm,
                               float* __restrict__ ws, int base_in, int base_out, float invN) {
    int oc = threadIdx.x;
    if (oc < 32) {
        float* stats = ws + OFS_STATS;
        float mean = stats[base_in + oc] * invN;
        float var  = stats[base_in + 32 + oc] * invN - mean * mean;
        float s = g[oc] * rsqrtf(var + 1e-5f);
        stats[base_out + oc]      = s;
        stats[base_out + 32 + oc] = bparm[oc] - mean * s;
    }
}

// ---------------- conv2 (BN1+ReLU folded at stage time) + BN2 stats ----------------
// grid 512 (b). block 192: ocg=tid&7 (4 oc each), tg=tid>>3 (4 t each)
// Weight LDS layout [k][oc]: 8 distinct b128 addrs/instr cover all 32 banks.
__global__ __launch_bounds__(192, 2) void conv2_kernel(const float* __restrict__ b2,
                                                       float* __restrict__ ws) {
    const float* w2p = ws + OFS_W2P;
    const float* y1 = ws + OFS_Y1;
    float* y2 = ws + OFS_Y2;
    float* stats = ws + OFS_STATS;
    int b = blockIdx.x;
    int tid = threadIdx.x;
    int ocg = tid & 7, tg = tid >> 3;
    int oc0 = ocg * 4, lt0 = tg * 4;

    __shared__ __align__(16) float a1s[500];
    __shared__ __align__(16) float w2s[800];   // [k][oc] 25*32
    __shared__ float sred[192];

    float acc[4][4];
#pragma unroll
    for (int a = 0; a < 4; ++a)
#pragma unroll
        for (int c = 0; c < 4; ++c) acc[a][c] = 0.f;

    for (int ic = 0; ic < 32; ++ic) {
        __syncthreads();
        float s1  = stats[128 + ic];
        float sh1 = stats[160 + ic];
        const float* yrow = y1 + (size_t)(b * 32 + ic) * T1;
        for (int i = tid; i < 124; i += 192) {
            float4 v = *(const float4*)(yrow + 4 * i);
            v.x = fmaxf(fmaf(v.x, s1, sh1), 0.f);
            v.y = fmaxf(fmaf(v.y, s1, sh1), 0.f);
            v.z = fmaxf(fmaf(v.z, s1, sh1), 0.f);
            v.w = fmaxf(fmaf(v.w, s1, sh1), 0.f);
            *(float4*)&a1s[4 * i] = v;
        }
        for (int i = tid; i < 200; i += 192)
            *(float4*)&w2s[4 * i] = *(const float4*)(w2p + ic * 800 + 4 * i);
        __syncthreads();

#pragma unroll 1
        for (int kp = 0; kp < 12; ++kp) {
            const int k = kp * 2;
            float4 wA = *(const float4*)&w2s[k * 32 + oc0];        // tap k
            float4 wB = *(const float4*)&w2s[(k + 1) * 32 + oc0];  // tap k+1
            float x0[4], x1[4];
#pragma unroll
            for (int jt = 0; jt < 4; ++jt) {
                int a = 20 * tg + 5 * jt + k;
                x0[jt] = a1s[a]; x1[jt] = a1s[a + 1];
            }
            float wk[4]  = {wA.x, wA.y, wA.z, wA.w};
            float wk1[4] = {wB.x, wB.y, wB.z, wB.w};
#pragma unroll
            for (int jo = 0; jo < 4; ++jo)
#pragma unroll
                for (int jt = 0; jt < 4; ++jt)
                    acc[jo][jt] = fmaf(wk1[jo], x1[jt], fmaf(wk[jo], x0[jt], acc[jo][jt]));
        }
        // k = 24 tail
        float4 wT = *(const float4*)&w2s[24 * 32 + oc0];
        float wt[4] = {wT.x, wT.y, wT.z, wT.w};
#pragma unroll
        for (int jt = 0; jt < 4; ++jt) {
            float xt_ = a1s[20 * tg + 5 * jt + 24];
#pragma unroll
            for (int jo = 0; jo < 4; ++jo) acc[jo][jt] = fmaf(wt[jo], xt_, acc[jo][jt]);
        }
    }

    float bias[4];
#pragma unroll
    for (int jo = 0; jo < 4; ++jo) bias[jo] = b2[oc0 + jo];

    float psum[4], psq[4];
#pragma unroll
    for (int jo = 0; jo < 4; ++jo) {
        float s = 0.f, q = 0.f;
#pragma unroll
        for (int jt = 0; jt < 4; ++jt) {
            int t2 = lt0 + jt;
            if (t2 < T2) {
                float v = acc[jo][jt] + bias[jo];
                y2[(size_t)(b * 32 + oc0 + jo) * T2 + t2] = v;
                s += v; q = fmaf(v, v, q);
            }
        }
        psum[jo] = s; psq[jo] = q;
    }
#pragma unroll
    for (int off = 32; off >= 8; off >>= 1) {
#pragma unroll
        for (int jo = 0; jo < 4; ++jo) {
            psum[jo] += __shfl_down(psum[jo], off, 64);
            psq[jo]  += __shfl_down(psq[jo],  off, 64);
        }
    }
    int lane = tid & 63, wvi = tid >> 6;   // 3 waves
    if (lane < 8) {
#pragma unroll
        for (int jo = 0; jo < 4; ++jo) {
            sred[((wvi * 8 + lane) * 4 + jo) * 2 + 0] = psum[jo];
            sred[((wvi * 8 + lane) * 4 + jo) * 2 + 1] = psq[jo];
        }
    }
    __syncthreads();
    if (tid < 64) {
        int oc = tid >> 1, which = tid & 1;
        int og = oc >> 2, jo = oc & 3;
        float v = 0.f;
#pragma unroll
        for (int w = 0; w < 3; ++w)
            v += sred[((w * 8 + og) * 4 + jo) * 2 + which];
        atomicAdd(&stats[64 + which * 32 + oc], v);
    }
}

// ---------------- projection + LayerNorm, writes xs[t][b][l] ----------------
__global__ __launch_bounds__(256, 2) void proj_kernel(const float* __restrict__ pw,
                                                      const float* __restrict__ pb,
                                                      const float* __restrict__ lng,
                                                      const float* __restrict__ lnb,
                                                      float* __restrict__ ws) {
    int b = blockIdx.x;
    int tid = threadIdx.x;
    __shared__ float a2s[3040];       // [f][t]
    __shared__ float pws[1056];       // [l][33]
    const float* stats = ws + OFS_STATS;
    const float* y2 = ws + OFS_Y2 + (size_t)b * (32 * T2);
    float* xsg = ws + OFS_XS;

    for (int f = 0; f < 32; ++f) {
        float s2  = stats[192 + f];
        float sh2 = stats[224 + f];
        if (tid < T2)
            a2s[f * T2 + tid] = fmaxf(fmaf(y2[f * T2 + tid], s2, sh2), 0.f);
    }
    for (int i = tid; i < 1024; i += 256)
        pws[(i >> 5) * 33 + (i & 31)] = pw[i];

    int l = tid & 31, ts = tid >> 5;
    float pbv = pb[l], lg = lng[l], lb = lnb[l];
    __syncthreads();

    for (int it = 0; it < 12; ++it) {
        int t = ts + 8 * it;
        if (t < T2) {
            float v = pbv;
#pragma unroll
            for (int f = 0; f < 32; ++f)
                v = fmaf(a2s[f * T2 + t], pws[l * 33 + f], v);
            float sum = v;
#pragma unroll
            for (int off = 16; off >= 1; off >>= 1) sum += __shfl_xor(sum, off, 64);
            float mean = sum * (1.f / 32.f);
            float d = v - mean;
            float q = d * d;
#pragma unroll
            for (int off = 16; off >= 1; off >>= 1) q += __shfl_xor(q, off, 64);
            float o = d * rsqrtf(q * (1.f / 32.f) + 1e-5f) * lg + lb;
            xsg[(size_t)t * (NB * 32) + b * 32 + l] = o;
        }
    }
}

// ---------------- PLRNN scan + pooled mean + output projection ----------------
// grid 512 (b), block 64 (one wave). No register array indexed by runtime value
// (would demote to scratch — R1/R2 lesson). half-dependent slices read from LDS.
__global__ __launch_bounds__(64)
__attribute__((amdgpu_waves_per_eu(1, 1)))
void scan_kernel(const float* __restrict__ Am,
                 const float* __restrict__ Wm,
                 const float* __restrict__ hbp,
                 const float* __restrict__ ow,
                 const float* __restrict__ ob,
                 const float* __restrict__ ws,
                 float* __restrict__ out) {
    int b = blockIdx.x;
    int lane = threadIdx.x;
    int l = lane & 31, half = lane >> 5;
    __shared__ __align__(16) float hs[32];
    __shared__ __align__(16) float hds[64];
    __shared__ float ows[1056];

    float Wc[32], WT[32], Ah[16];
#pragma unroll
    for (int j = 0; j < 32; ++j) Wc[j] = Wm[j * HIDD + lane];          // W[j][lane]
#pragma unroll
    for (int m = 0; m < 32; ++m) WT[m] = Wm[l * HIDD + half * 32 + m]; // W[l][m-half]
#pragma unroll
    for (int j = 0; j < 16; ++j) Ah[j] = Am[l * 32 + half * 16 + j];   // A[l][j-half]
    float hbv = hbp[lane];
    for (int i = lane; i < 1024; i += 64)
        ows[(i >> 5) * 33 + (i & 31)] = ow[i];

    const float* xsg = ws + OFS_XS + b * 32;
    if (lane < 32) hs[l] = 0.f;
    float xv = xsg[l];
    float pool = 0.f;
    __syncthreads();

    for (int t = 0; t < T2; ++t) {
        __syncthreads();
        float4 hv[8];
#pragma unroll
        for (int q = 0; q < 8; ++q) hv[q] = *(const float4*)&hs[4 * q];
        float a0 = hbv, a1 = 0.f, a2 = 0.f, a3 = 0.f;
#pragma unroll
        for (int q = 0; q < 8; ++q) {
            a0 = fmaf(Wc[4 * q + 0], hv[q].x, a0);
            a1 = fmaf(Wc[4 * q + 1], hv[q].y, a1);
            a2 = fmaf(Wc[4 * q + 2], hv[q].z, a2);
            a3 = fmaf(Wc[4 * q + 3], hv[q].w, a3);
        }
        float hid = fmaxf((a0 + a1) + (a2 + a3), 0.f);
        float4 hl[4];
#pragma unroll
        for (int q = 0; q < 4; ++q) hl[q] = *(const float4*)&hs[half * 16 + 4 * q];
        float l0 = 0.f, l1 = 0.f;
#pragma unroll
        for (int q = 0; q < 4; ++q) {
            l0 = fmaf(Ah[4 * q + 0], hl[q].x, l0);
            l1 = fmaf(Ah[4 * q + 1], hl[q].y, l1);
            l0 = fmaf(Ah[4 * q + 2], hl[q].z, l0);
            l1 = fmaf(Ah[4 * q + 3], hl[q].w, l1);
        }
        float lin = l0 + l1;
        hds[lane] = hid;
        __syncthreads();
        float n0 = 0.f, n1 = 0.f, n2 = 0.f, n3 = 0.f;
#pragma unroll
        for (int q = 0; q < 8; ++q) {
            float4 d4 = *(const float4*)&hds[half * 32 + 4 * q];
            n0 = fmaf(WT[4 * q + 0], d4.x, n0);
            n1 = fmaf(WT[4 * q + 1], d4.y, n1);
            n2 = fmaf(WT[4 * q + 2], d4.z, n2);
            n3 = fmaf(WT[4 * q + 3], d4.w, n3);
        }
        float part = (n0 + n1) + (n2 + n3) + lin;
        part += __shfl_xor(part, 32, 64);
        float hnew = part + xv;
        pool += hnew;
        if (t + 1 < T2) xv = xsg[(size_t)(t + 1) * (NB * 32) + l];
        if (lane < 32) hs[l] = hnew;
    }

    __syncthreads();
    if (lane < 32) hs[l] = pool * (1.f / 95.f);
    __syncthreads();
    if (lane < 32) {
        float4 p0 = *(const float4*)&hs[0];
        float4 p1 = *(const float4*)&hs[4];
        float4 p2 = *(const float4*)&hs[8];
        float4 p3 = *(const float4*)&hs[12];
        float4 p4 = *(const float4*)&hs[16];
        float4 p5 = *(const float4*)&hs[20];
        float4 p6 = *(const float4*)&hs[24];
        float4 p7 = *(const float4*)&hs[28];
        float o = ob[l];
        const float* owr = &ows[l * 33];
        o = fmaf(owr[0],  p0.x, o); o = fmaf(owr[1],  p0.y, o);
        o = fmaf(owr[2],  p0.z, o); o = fmaf(owr[3],  p0.w, o);
        o = fmaf(owr[4],  p1.x, o); o = fmaf(owr[5],  p1.y, o);
        o = fmaf(owr[6],  p1.z, o); o = fmaf(owr[7],  p1.w, o);
        o = fmaf(owr[8],  p2.x, o); o = fmaf(owr[9],  p2.y, o);
        o = fmaf(owr[10], p2.z, o); o = fmaf(owr[11], p2.w, o);
        o = fmaf(owr[12], p3.x, o); o = fmaf(owr[13], p3.y, o);
        o = fmaf(owr[14], p3.z, o); o = fmaf(owr[15], p3.w, o);
        o = fmaf(owr[16], p4.x, o); o = fmaf(owr[17], p4.y, o);
        o = fmaf(owr[18], p4.z, o); o = fmaf(owr[19], p4.w, o);
        o = fmaf(owr[20], p5.x, o); o = fmaf(owr[21], p5.y, o);
        o = fmaf(owr[22], p5.z, o); o = fmaf(owr[23], p5.w, o);
        o = fmaf(owr[24], p6.x, o); o = fmaf(owr[25], p6.y, o);
        o = fmaf(owr[26], p6.z, o); o = fmaf(owr[27], p6.w, o);
        o = fmaf(owr[28], p7.x, o); o = fmaf(owr[29], p7.y, o);
        o = fmaf(owr[30], p7.z, o); o = fmaf(owr[31], p7.w, o);
        out[b * 32 + l] = o;
    }
}

extern "C" void kernel_launch(void* const* d_in, const int* in_sizes, int n_in,
                              void* d_out, int out_size, void* d_ws, size_t ws_size,
                              hipStream_t stream) {
    (void)in_sizes; (void)n_in; (void)out_size; (void)ws_size;
    const float* x   = (const float*)d_in[0];
    const float* w1  = (const float*)d_in[1];
    const float* b1  = (const float*)d_in[2];
    const float* g1  = (const float*)d_in[3];
    const float* be1 = (const float*)d_in[4];
    const float* w2  = (const float*)d_in[5];
    const float* b2  = (const float*)d_in[6];
    const float* g2  = (const float*)d_in[7];
    const float* be2 = (const float*)d_in[8];
    const float* pw  = (const float*)d_in[9];
    const float* pb  = (const float*)d_in[10];
    const float* lng = (const float*)d_in[11];
    const float* lnb = (const float*)d_in[12];
    const float* Am  = (const float*)d_in[13];
    const float* Wm  = (const float*)d_in[14];
    const float* hb  = (const float*)d_in[15];
    const float* ow  = (const float*)d_in[16];
    const float* ob  = (const float*)d_in[17];
    float* ws  = (float*)d_ws;
    float* out = (float*)d_out;

    prep_kernel<<<176, 256, 0, stream>>>(w1, w2, ws);
    conv1_kernel<<<1024, 128, 0, stream>>>(x, b1, ws);
    bnstats_kernel<<<1, 64, 0, stream>>>(g1, be1, ws, 0, 128, 1.f / 253952.f);
    conv2_kernel<<<512, 192, 0, stream>>>(b2, ws);
    bnstats_kernel<<<1, 64, 0, stream>>>(g2, be2, ws, 64, 192, 1.f / 48640.f);
    proj_kernel<<<512, 256, 0, stream>>>(pw, pb, lng, lnb, ws);
    scan_kernel<<<512, 64, 0, stream>>>(Am, Wm, hb, ow, ob, ws, out);
}